// Round 16
// baseline (646.868 us; speedup 1.0000x reference)
//
#include <hip/hip_runtime.h>

typedef __attribute__((ext_vector_type(4))) float f32x4;
typedef _Float16 f16;
typedef __attribute__((ext_vector_type(2))) _Float16 f16x2;
typedef __attribute__((ext_vector_type(8))) _Float16 f16x8;

#define T_LEN 2048
#define B_SZ 256
#define FEATN 128
#define H 50
#define H3 150
#define XW_STRIDE 160

#define UROW 168  // f16 units per lane row = 336B; conflict-free b128 stride

__device__ __forceinline__ float rcpf(float x) { return __builtin_amdgcn_rcpf(x); }

// f32-accumulating f16-pair MAC (proven numerics; used for the h-gate).
__device__ __forceinline__ float dot2f(f16x2 a, f16x2 b, float c) {
#if __has_builtin(__builtin_amdgcn_fdot2)
  return __builtin_amdgcn_fdot2(a, b, c, false);
#else
  return fmaf((float)a[1], (float)b[1], fmaf((float)a[0], (float)b[0], c));
#endif
}

// ---------------- Phase 1: xw[m][k] = x[m][:] @ W[:][k]  (f16 out, no bias) ----
__global__ __launch_bounds__(256) void xw_gemm(const float* __restrict__ x,
                                               const float* __restrict__ W,
                                               f16* __restrict__ xw) {
  __shared__ f16 Wt[160 * 136];  // [n][k], row stride 136 halves
  const int tid = threadIdx.x;
  for (int idx = tid; idx < FEATN * H3; idx += 256) {
    int f = idx / H3;
    int n = idx - f * H3;
    Wt[n * 136 + f] = (f16)W[idx];
  }
  for (int idx = tid; idx < 10 * FEATN; idx += 256) {  // zero-pad n = 150..159
    int n = H3 + (idx >> 7);
    int f = idx & 127;
    Wt[n * 136 + f] = (f16)0.f;
  }
  __syncthreads();

  const int wid = tid >> 6;
  const int lane = tid & 63;
  const int l15 = lane & 15;
  const int g = lane >> 4;
  const long row0 = (long)blockIdx.x * 128 + wid * 32;

  f16x8 a[2][4];
#pragma unroll
  for (int sub = 0; sub < 2; ++sub) {
    const float* xp = x + (row0 + sub * 16 + l15) * FEATN + g * 8;
#pragma unroll
    for (int kk = 0; kk < 4; ++kk) {
      f32x4 p0 = *(const f32x4*)(xp + kk * 32);
      f32x4 p1 = *(const f32x4*)(xp + kk * 32 + 4);
      f16x8 v;
      v[0] = (f16)p0[0]; v[1] = (f16)p0[1]; v[2] = (f16)p0[2]; v[3] = (f16)p0[3];
      v[4] = (f16)p1[0]; v[5] = (f16)p1[1]; v[6] = (f16)p1[2]; v[7] = (f16)p1[3];
      a[sub][kk] = v;
    }
  }

  for (int nt = 0; nt < 10; ++nt) {
    const f16* bp = &Wt[(nt * 16 + l15) * 136 + g * 8];
    f16x8 bf0 = *(const f16x8*)(bp);
    f16x8 bf1 = *(const f16x8*)(bp + 32);
    f16x8 bf2 = *(const f16x8*)(bp + 64);
    f16x8 bf3 = *(const f16x8*)(bp + 96);
    f32x4 acc0 = {0.f, 0.f, 0.f, 0.f};
    f32x4 acc1 = {0.f, 0.f, 0.f, 0.f};
    acc0 = __builtin_amdgcn_mfma_f32_16x16x32_f16(a[0][0], bf0, acc0, 0, 0, 0);
    acc0 = __builtin_amdgcn_mfma_f32_16x16x32_f16(a[0][1], bf1, acc0, 0, 0, 0);
    acc0 = __builtin_amdgcn_mfma_f32_16x16x32_f16(a[0][2], bf2, acc0, 0, 0, 0);
    acc0 = __builtin_amdgcn_mfma_f32_16x16x32_f16(a[0][3], bf3, acc0, 0, 0, 0);
    acc1 = __builtin_amdgcn_mfma_f32_16x16x32_f16(a[1][0], bf0, acc1, 0, 0, 0);
    acc1 = __builtin_amdgcn_mfma_f32_16x16x32_f16(a[1][1], bf1, acc1, 0, 0, 0);
    acc1 = __builtin_amdgcn_mfma_f32_16x16x32_f16(a[1][2], bf2, acc1, 0, 0, 0);
    acc1 = __builtin_amdgcn_mfma_f32_16x16x32_f16(a[1][3], bf3, acc1, 0, 0, 0);
    int col = nt * 16 + l15;
    if (col < H3) {
#pragma unroll
      for (int r = 0; r < 4; ++r) {
        long rowA = row0 + g * 4 + r;
        xw[rowA * XW_STRIDE + col] = (f16)acc0[r];
        xw[(rowA + 16) * XW_STRIDE + col] = (f16)acc1[r];
      }
    }
  }
}

// ---------------- Phase 2: one wave64 per row; pk_fma z/r + f32 h-gate -------
// Lane l<50 owns h[l]. U in per-lane LDS rows; h broadcast via uniform b128.
// Issue-bound (r11/r15 evidence) -> cut instructions: z/r dot chains use
// v_pk_fma_f16 (1 instr per f16 pair; f16 accum error damped 4x by sigmoid
// slope), h-gate keeps the f32-accumulating path (tanh is undamped).
__global__ __launch_bounds__(64, 1) void gru_head64(const f16* __restrict__ xw,
                                                    const float* __restrict__ U,
                                                    const float* __restrict__ bias,
                                                    const float* __restrict__ W2,
                                                    const float* __restrict__ b2,
                                                    float* __restrict__ out) {
  __shared__ __align__(16) f16 h_lds16[64];
  __shared__ __align__(16) f16 Ul[64 * UROW];  // [lane][uz:0..|ur:56..|uh:112..]
  __shared__ float fin[52];
  __shared__ float red[8];
  const int l = threadIdx.x;
  const int b = blockIdx.x;
  const int lc = l < H ? l : H - 1;
  const bool act = l < H;
  const long base = (long)b * T_LEN * XW_STRIDE;

  f16* myU = Ul + l * UROW;
#pragma unroll
  for (int c = 0; c < 25; ++c) {
    *(f16x2*)(myU + 2 * c) =
        (f16x2){(f16)U[(2 * c) * H3 + lc], (f16)U[(2 * c + 1) * H3 + lc]};
    *(f16x2*)(myU + 56 + 2 * c) =
        (f16x2){(f16)U[(2 * c) * H3 + H + lc], (f16)U[(2 * c + 1) * H3 + H + lc]};
    *(f16x2*)(myU + 112 + 2 * c) =
        (f16x2){(f16)U[(2 * c) * H3 + 2 * H + lc],
                (f16)U[(2 * c + 1) * H3 + 2 * H + lc]};
  }
  const float bz = bias[lc] + bias[H3 + lc];
  const float br = bias[H + lc] + bias[H3 + H + lc];
  const float b0h = bias[2 * H + lc];
  const float b1h = bias[H3 + 2 * H + lc];

  float hreg = 0.f;
  h_lds16[l] = (f16)0.f;

  const f16* q = xw + base + lc;
  f16 pz[4], pr[4], ph[4];
#pragma unroll
  for (int p = 0; p < 4; ++p) {
    pz[p] = q[p * XW_STRIDE];
    pr[p] = q[p * XW_STRIDE + H];
    ph[p] = q[p * XW_STRIDE + 2 * H];
  }

  const f16x8* hp8 = (const f16x8*)h_lds16;
  const f16x8* uzp = (const f16x8*)(myU);
  const f16x8* urp = (const f16x8*)(myU + 56);
  const f16x8* uhp = (const f16x8*)(myU + 112);

#define EX4(DST, SRC, B)                                                      \
  DST[B] = __builtin_shufflevector(SRC, SRC, 0, 1);                           \
  DST[B + 1] = __builtin_shufflevector(SRC, SRC, 2, 3);                       \
  DST[B + 2] = __builtin_shufflevector(SRC, SRC, 4, 5);                       \
  DST[B + 3] = __builtin_shufflevector(SRC, SRC, 6, 7);

#define STEP(P, PF)                                                           \
    {                                                                         \
      /* capture current xw BEFORE refilling the ring slot */                 \
      float xzf = (float)pz[P];                                               \
      float xrf = (float)pr[P];                                               \
      float xhf = (float)ph[P];                                               \
      if (PF) {                                                               \
        pz[P] = q[(P + 4) * XW_STRIDE];                                       \
        pr[P] = q[(P + 4) * XW_STRIDE + H];                                   \
        ph[P] = q[(P + 4) * XW_STRIDE + 2 * H];                               \
      }                                                                       \
      f16x2 uzv[25], urv[25], uhv[25], hv[25];                                \
      _Pragma("unroll")                                                       \
      for (int i = 0; i < 6; ++i) { f16x8 t = uzp[i]; EX4(uzv, t, 4 * i) }    \
      uzv[24] = *(const f16x2*)(myU + 48);                                    \
      _Pragma("unroll")                                                       \
      for (int i = 0; i < 6; ++i) { f16x8 t = urp[i]; EX4(urv, t, 4 * i) }    \
      urv[24] = *(const f16x2*)(myU + 56 + 48);                               \
      _Pragma("unroll")                                                       \
      for (int i = 0; i < 6; ++i) { f16x8 t = uhp[i]; EX4(uhv, t, 4 * i) }    \
      uhv[24] = *(const f16x2*)(myU + 112 + 48);                              \
      {                                                                       \
        f16x8 w0 = hp8[0], w1 = hp8[1], w2 = hp8[2];                          \
        f16x8 w3 = hp8[3], w4 = hp8[4], w5 = hp8[5];                          \
        EX4(hv, w0, 0) EX4(hv, w1, 4) EX4(hv, w2, 8)                          \
        EX4(hv, w3, 12) EX4(hv, w4, 16) EX4(hv, w5, 20)                       \
        hv[24] = *(const f16x2*)(h_lds16 + 48);                               \
      }                                                                       \
      /* z/r: packed f16 FMA chains (1 instr per pair, 2-way split) */        \
      f16x2 az0 = (f16x2){(f16)0.f, (f16)0.f}, az1 = az0;                     \
      f16x2 ar0 = az0, ar1 = az0;                                             \
      float sh0 = b1h, sh1 = 0.f;                                             \
      _Pragma("unroll")                                                       \
      for (int p = 0; p < 25; ++p) {                                          \
        if (p & 1) {                                                          \
          az1 = hv[p] * uzv[p] + az1;                                         \
          ar1 = hv[p] * urv[p] + ar1;                                         \
          sh1 = dot2f(hv[p], uhv[p], sh1);                                    \
        } else {                                                              \
          az0 = hv[p] * uzv[p] + az0;                                         \
          ar0 = hv[p] * urv[p] + ar0;                                         \
          sh0 = dot2f(hv[p], uhv[p], sh0);                                    \
        }                                                                     \
      }                                                                       \
      float az = ((float)az0[0] + (float)az0[1]) +                            \
                 ((float)az1[0] + (float)az1[1]) + (bz + xzf);                \
      float ar = ((float)ar0[0] + (float)ar0[1]) +                            \
                 ((float)ar1[0] + (float)ar1[1]) + (br + xrf);                \
      float er = __expf(-ar);                                                 \
      float ez = __expf(-az);                                                 \
      float rr = rcpf(1.f + er);                                              \
      float zz = rcpf(1.f + ez);                                              \
      float ah = fmaf(rr, sh0 + sh1, xhf + b0h);                              \
      float eh = __expf(-2.f * ah);                                           \
      float th = fmaf(2.f, rcpf(1.f + eh), -1.f);                             \
      hreg = fmaf(zz, hreg - th, th);                                         \
      h_lds16[l] = (f16)hreg;                                                 \
    }

  for (int t0 = 0; t0 < T_LEN - 4; t0 += 4) {
    STEP(0, 1) STEP(1, 1) STEP(2, 1) STEP(3, 1)
    q += 4 * XW_STRIDE;
  }
  // final group: no prefetch (avoids OOB reads past the workspace)
  STEP(0, 0) STEP(1, 0) STEP(2, 0) STEP(3, 0)
#undef STEP
#undef EX4

  // LeakyReLU(0.3) + dense(50->8) + softmax, single wave, in-order LDS
  if (act) {
    fin[l] = hreg >= 0.f ? hreg : 0.3f * hreg;
  }
  if (l < 8) {
    float acc = b2[l];
#pragma unroll
    for (int j = 0; j < H; ++j) acc = fmaf(fin[j], W2[j * 8 + l], acc);
    red[l] = acc;
  }
  if (l < 8) {
    float m = red[0];
#pragma unroll
    for (int i = 1; i < 8; ++i) m = fmaxf(m, red[i]);
    float s = 0.f;
#pragma unroll
    for (int i = 0; i < 8; ++i) s += __expf(red[i] - m);
    out[b * 8 + l] = __expf(red[l] - m) / s;
  }
}

extern "C" void kernel_launch(void* const* d_in, const int* in_sizes, int n_in,
                              void* d_out, int out_size, void* d_ws, size_t ws_size,
                              hipStream_t stream) {
  const float* x = (const float*)d_in[0];
  const float* W = (const float*)d_in[1];
  const float* U = (const float*)d_in[2];
  const float* bias = (const float*)d_in[3];
  const float* W2 = (const float*)d_in[4];
  const float* b2 = (const float*)d_in[5];
  float* out = (float*)d_out;
  f16* xw = (f16*)d_ws;  // [B*T][160] f16, ~168 MB

  xw_gemm<<<4096, 256, 0, stream>>>(x, W, xw);
  gru_head64<<<256, 64, 0, stream>>>(xw, U, bias, W2, b2, out);
}

// Round 17
// 640.652 us; speedup vs baseline: 1.0097x; 1.0097x over previous
//
#include <hip/hip_runtime.h>

typedef __attribute__((ext_vector_type(4))) float f32x4;
typedef _Float16 f16;
typedef __attribute__((ext_vector_type(2))) _Float16 f16x2;
typedef __attribute__((ext_vector_type(8))) _Float16 f16x8;

#define T_LEN 2048
#define B_SZ 256
#define FEATN 128
#define H 50
#define H3 150
#define XW_STRIDE 160

__device__ __forceinline__ float rcpf(float x) { return __builtin_amdgcn_rcpf(x); }

// UNCONDITIONAL fdot2 — ground-truth test. If gfx950 lacks it, this fails to
// compile (informative). If the __has_builtin guard was silently false, all
// rounds since r3 ran the 2-instr v_fma_mix fallback — the invariant ~533us.
__device__ __forceinline__ float dot2f(f16x2 a, f16x2 b, float c) {
  return __builtin_amdgcn_fdot2(a, b, c, false);
}

// ---------------- Phase 1: xw[m][k] = x[m][:] @ W[:][k]  (f16 out, no bias) ----
__global__ __launch_bounds__(256) void xw_gemm(const float* __restrict__ x,
                                               const float* __restrict__ W,
                                               f16* __restrict__ xw) {
  __shared__ f16 Wt[160 * 136];  // [n][k], row stride 136 halves
  const int tid = threadIdx.x;
  for (int idx = tid; idx < FEATN * H3; idx += 256) {
    int f = idx / H3;
    int n = idx - f * H3;
    Wt[n * 136 + f] = (f16)W[idx];
  }
  for (int idx = tid; idx < 10 * FEATN; idx += 256) {  // zero-pad n = 150..159
    int n = H3 + (idx >> 7);
    int f = idx & 127;
    Wt[n * 136 + f] = (f16)0.f;
  }
  __syncthreads();

  const int wid = tid >> 6;
  const int lane = tid & 63;
  const int l15 = lane & 15;
  const int g = lane >> 4;
  const long row0 = (long)blockIdx.x * 128 + wid * 32;

  f16x8 a[2][4];
#pragma unroll
  for (int sub = 0; sub < 2; ++sub) {
    const float* xp = x + (row0 + sub * 16 + l15) * FEATN + g * 8;
#pragma unroll
    for (int kk = 0; kk < 4; ++kk) {
      f32x4 p0 = *(const f32x4*)(xp + kk * 32);
      f32x4 p1 = *(const f32x4*)(xp + kk * 32 + 4);
      f16x8 v;
      v[0] = (f16)p0[0]; v[1] = (f16)p0[1]; v[2] = (f16)p0[2]; v[3] = (f16)p0[3];
      v[4] = (f16)p1[0]; v[5] = (f16)p1[1]; v[6] = (f16)p1[2]; v[7] = (f16)p1[3];
      a[sub][kk] = v;
    }
  }

  for (int nt = 0; nt < 10; ++nt) {
    const f16* bp = &Wt[(nt * 16 + l15) * 136 + g * 8];
    f16x8 bf0 = *(const f16x8*)(bp);
    f16x8 bf1 = *(const f16x8*)(bp + 32);
    f16x8 bf2 = *(const f16x8*)(bp + 64);
    f16x8 bf3 = *(const f16x8*)(bp + 96);
    f32x4 acc0 = {0.f, 0.f, 0.f, 0.f};
    f32x4 acc1 = {0.f, 0.f, 0.f, 0.f};
    acc0 = __builtin_amdgcn_mfma_f32_16x16x32_f16(a[0][0], bf0, acc0, 0, 0, 0);
    acc0 = __builtin_amdgcn_mfma_f32_16x16x32_f16(a[0][1], bf1, acc0, 0, 0, 0);
    acc0 = __builtin_amdgcn_mfma_f32_16x16x32_f16(a[0][2], bf2, acc0, 0, 0, 0);
    acc0 = __builtin_amdgcn_mfma_f32_16x16x32_f16(a[0][3], bf3, acc0, 0, 0, 0);
    acc1 = __builtin_amdgcn_mfma_f32_16x16x32_f16(a[1][0], bf0, acc1, 0, 0, 0);
    acc1 = __builtin_amdgcn_mfma_f32_16x16x32_f16(a[1][1], bf1, acc1, 0, 0, 0);
    acc1 = __builtin_amdgcn_mfma_f32_16x16x32_f16(a[1][2], bf2, acc1, 0, 0, 0);
    acc1 = __builtin_amdgcn_mfma_f32_16x16x32_f16(a[1][3], bf3, acc1, 0, 0, 0);
    int col = nt * 16 + l15;
    if (col < H3) {
#pragma unroll
      for (int r = 0; r < 4; ++r) {
        long rowA = row0 + g * 4 + r;
        xw[rowA * XW_STRIDE + col] = (f16)acc0[r];
        xw[(rowA + 16) * XW_STRIDE + col] = (f16)acc1[r];
      }
    }
  }
}

// ---------------- Phase 2: one wave64 per row (r10 base, fdot2 forced) -------
// Lane l<50 owns h[l]; h broadcast via uniform-address b128 f16x8 LDS reads
// (one wave's DS ops are in-order -> no fences; vmcnt prefetch in flight).
// Ring refill + cvts placed between the h-read issue (end of prev step) and
// the dots to cover part of the DS turnaround.
__global__ __launch_bounds__(64, 1) void gru_head64(const f16* __restrict__ xw,
                                                    const float* __restrict__ U,
                                                    const float* __restrict__ bias,
                                                    const float* __restrict__ W2,
                                                    const float* __restrict__ b2,
                                                    float* __restrict__ out) {
  __shared__ __align__(16) f16 h_lds16[64];
  __shared__ float fin[52];
  __shared__ float red[8];
  const int l = threadIdx.x;
  const int b = blockIdx.x;
  const int lc = l < H ? l : H - 1;
  const bool act = l < H;
  const long base = (long)b * T_LEN * XW_STRIDE;

  // U columns (z,r,h) for this lane, packed as f16 pairs over j: 75 VGPRs.
  f16x2 uz2[25], ur2[25], uh2[25];
#pragma unroll
  for (int c = 0; c < 25; ++c) {
    uz2[c][0] = (f16)U[(2 * c) * H3 + lc];
    uz2[c][1] = (f16)U[(2 * c + 1) * H3 + lc];
    ur2[c][0] = (f16)U[(2 * c) * H3 + H + lc];
    ur2[c][1] = (f16)U[(2 * c + 1) * H3 + H + lc];
    uh2[c][0] = (f16)U[(2 * c) * H3 + 2 * H + lc];
    uh2[c][1] = (f16)U[(2 * c + 1) * H3 + 2 * H + lc];
  }
  const float bz = bias[lc] + bias[H3 + lc];
  const float br = bias[H + lc] + bias[H3 + H + lc];
  const float b0h = bias[2 * H + lc];
  const float b1h = bias[H3 + 2 * H + lc];

  float hreg = 0.f;
  h_lds16[l] = (f16)0.f;

  const f16* q = xw + base + lc;
  f16 pz[4], pr[4], ph[4];
#pragma unroll
  for (int p = 0; p < 4; ++p) {
    pz[p] = q[p * XW_STRIDE];
    pr[p] = q[p * XW_STRIDE + H];
    ph[p] = q[p * XW_STRIDE + 2 * H];
  }

  const f16x8* hp8 = (const f16x8*)h_lds16;

#define STEP(P, PF)                                                           \
    {                                                                         \
      /* h-broadcast reads issue first (right after prev step's store) */     \
      f16x8 w0 = hp8[0], w1 = hp8[1], w2 = hp8[2];                            \
      f16x8 w3 = hp8[3], w4 = hp8[4], w5 = hp8[5];                            \
      f16x2 w6 = *(const f16x2*)(h_lds16 + 48);                               \
      /* cover DS turnaround: capture xw, refill ring (VMEM), cvts */         \
      float xzf = (float)pz[P];                                               \
      float xrf = (float)pr[P];                                               \
      float xhf = (float)ph[P];                                               \
      if (PF) {                                                               \
        pz[P] = q[(P + 4) * XW_STRIDE];                                       \
        pr[P] = q[(P + 4) * XW_STRIDE + H];                                   \
        ph[P] = q[(P + 4) * XW_STRIDE + 2 * H];                               \
      }                                                                       \
      f16x2 hv[25];                                                           \
      hv[0] = __builtin_shufflevector(w0, w0, 0, 1);                          \
      hv[1] = __builtin_shufflevector(w0, w0, 2, 3);                          \
      hv[2] = __builtin_shufflevector(w0, w0, 4, 5);                          \
      hv[3] = __builtin_shufflevector(w0, w0, 6, 7);                          \
      hv[4] = __builtin_shufflevector(w1, w1, 0, 1);                          \
      hv[5] = __builtin_shufflevector(w1, w1, 2, 3);                          \
      hv[6] = __builtin_shufflevector(w1, w1, 4, 5);                          \
      hv[7] = __builtin_shufflevector(w1, w1, 6, 7);                          \
      hv[8] = __builtin_shufflevector(w2, w2, 0, 1);                          \
      hv[9] = __builtin_shufflevector(w2, w2, 2, 3);                          \
      hv[10] = __builtin_shufflevector(w2, w2, 4, 5);                         \
      hv[11] = __builtin_shufflevector(w2, w2, 6, 7);                         \
      hv[12] = __builtin_shufflevector(w3, w3, 0, 1);                         \
      hv[13] = __builtin_shufflevector(w3, w3, 2, 3);                         \
      hv[14] = __builtin_shufflevector(w3, w3, 4, 5);                         \
      hv[15] = __builtin_shufflevector(w3, w3, 6, 7);                         \
      hv[16] = __builtin_shufflevector(w4, w4, 0, 1);                         \
      hv[17] = __builtin_shufflevector(w4, w4, 2, 3);                         \
      hv[18] = __builtin_shufflevector(w4, w4, 4, 5);                         \
      hv[19] = __builtin_shufflevector(w4, w4, 6, 7);                         \
      hv[20] = __builtin_shufflevector(w5, w5, 0, 1);                         \
      hv[21] = __builtin_shufflevector(w5, w5, 2, 3);                         \
      hv[22] = __builtin_shufflevector(w5, w5, 4, 5);                         \
      hv[23] = __builtin_shufflevector(w5, w5, 6, 7);                         \
      hv[24] = w6;                                                            \
      float sz0 = bz, sr0 = br, sh0 = b1h;                                    \
      float sz1 = 0.f, sr1 = 0.f, sh1 = 0.f;                                  \
      _Pragma("unroll")                                                       \
      for (int p = 0; p < 25; ++p) {                                          \
        if (p & 1) {                                                          \
          sz1 = dot2f(hv[p], uz2[p], sz1);                                    \
          sr1 = dot2f(hv[p], ur2[p], sr1);                                    \
          sh1 = dot2f(hv[p], uh2[p], sh1);                                    \
        } else {                                                              \
          sz0 = dot2f(hv[p], uz2[p], sz0);                                    \
          sr0 = dot2f(hv[p], ur2[p], sr0);                                    \
          sh0 = dot2f(hv[p], uh2[p], sh0);                                    \
        }                                                                     \
      }                                                                       \
      float ar = (sr0 + sr1) + xrf;                                           \
      float er = __expf(-ar);                                                 \
      float az = (sz0 + sz1) + xzf;                                           \
      float ez = __expf(-az);                                                 \
      float rr = rcpf(1.f + er);                                              \
      float zz = rcpf(1.f + ez);                                              \
      float ah = fmaf(rr, sh0 + sh1, xhf + b0h);                              \
      float eh = __expf(-2.f * ah);                                           \
      float th = fmaf(2.f, rcpf(1.f + eh), -1.f);                             \
      hreg = fmaf(zz, hreg - th, th);                                         \
      h_lds16[l] = (f16)hreg;                                                 \
    }

  for (int t0 = 0; t0 < T_LEN - 4; t0 += 4) {
    STEP(0, 1) STEP(1, 1) STEP(2, 1) STEP(3, 1)
    q += 4 * XW_STRIDE;
  }
  // final group: no prefetch (avoids OOB reads past the workspace)
  STEP(0, 0) STEP(1, 0) STEP(2, 0) STEP(3, 0)
#undef STEP

  // LeakyReLU(0.3) + dense(50->8) + softmax, single wave, in-order LDS
  if (act) {
    fin[l] = hreg >= 0.f ? hreg : 0.3f * hreg;
  }
  if (l < 8) {
    float acc = b2[l];
#pragma unroll
    for (int j = 0; j < H; ++j) acc = fmaf(fin[j], W2[j * 8 + l], acc);
    red[l] = acc;
  }
  if (l < 8) {
    float m = red[0];
#pragma unroll
    for (int i = 1; i < 8; ++i) m = fmaxf(m, red[i]);
    float s = 0.f;
#pragma unroll
    for (int i = 0; i < 8; ++i) s += __expf(red[i] - m);
    out[b * 8 + l] = __expf(red[l] - m) / s;
  }
}

extern "C" void kernel_launch(void* const* d_in, const int* in_sizes, int n_in,
                              void* d_out, int out_size, void* d_ws, size_t ws_size,
                              hipStream_t stream) {
  const float* x = (const float*)d_in[0];
  const float* W = (const float*)d_in[1];
  const float* U = (const float*)d_in[2];
  const float* bias = (const float*)d_in[3];
  const float* W2 = (const float*)d_in[4];
  const float* b2 = (const float*)d_in[5];
  float* out = (float*)d_out;
  f16* xw = (f16*)d_ws;  // [B*T][160] f16, ~168 MB

  xw_gemm<<<4096, 256, 0, stream>>>(x, W, xw);
  gru_head64<<<256, 64, 0, stream>>>(xw, U, bias, W2, b2, out);
}